// Round 13
// baseline (380.291 us; speedup 1.0000x reference)
//
#include <hip/hip_runtime.h>

#define NNODES 200000
#define NEDGES 6400000
#define FIN 7
#define FH1 32
#define FH2 16
#define NC 2

// bucketing
#define WB 128                       // nodes per bucket
#define WB_SHIFT 7
#define NBUCK ((NNODES + WB - 1) / WB)   // 1563
#define BT 512                        // p2 block threads
#define NBLK 512                      // p2 grid (2 blocks/CU)
#define CHUNK (NEDGES / NBLK)         // 12500 exact
#define EPT ((CHUNK + BT - 1) / BT)   // 25 edges per thread
#define PSHIFT 18
#define SRCMASK ((1u << PSHIFT) - 1)

// padded per-bucket region in recs: mean 4096, sd 64 -> 8-sigma margin
#define RSTRIDE 4608
// per-bucket LDS staging capacity (p2b only)
#define SCAP 5120

// ---------------- zero bucket cursors ----------------

__global__ __launch_bounds__(256) void zero_cnt(int* __restrict__ cnt) {
    int i = blockIdx.x * 256 + threadIdx.x;
    if (i < NBUCK) cnt[i] = 0;
}

// ---------------- P2: rank-capture LDS chunk-sort (spill-free, round-11 proven) ----------------

__global__ __launch_bounds__(BT, 4) void p2_sortres(const int* __restrict__ ei,
                                                    int* __restrict__ bucket_cur,
                                                    unsigned int* __restrict__ recs) {
    __shared__ int sorted[CHUNK];    // 50000 B
    __shared__ int lcur[NBUCK];      // counts -> exclusive starts
    __shared__ int gbase[NBUCK];     // reserved global base per bucket run
    __shared__ int sm[BT];           // scan temp (total 64552 B <= 64K)
    int t = threadIdx.x;
    int blk = blockIdx.x;

    for (int i = t; i < NBUCK; i += BT) lcur[i] = 0;
    __syncthreads();

    // 1. histogram with rank capture: rb[j] = (bucket << 14) | rank
    int ebase = blk * CHUNK;
    int rb[EPT];
#pragma unroll
    for (int j = 0; j < EPT; ++j) {
        int idx = j * BT + t;
        if (idx < CHUNK) {
            int d = ei[NEDGES + ebase + idx];
            int b = d >> WB_SHIFT;
            int rank = atomicAdd(&lcur[b], 1);       // rank < 12500 < 2^14
            rb[j] = (b << 14) | rank;
        }
    }
    __syncthreads();

    // 2. exclusive scan of counts -> starts + global run reservation
    int base4 = t * 4;
    int loc[4];
    int s = 0;
#pragma unroll
    for (int k = 0; k < 4; ++k) {
        int idx = base4 + k;
        int v = (idx < NBUCK) ? lcur[idx] : 0;
        loc[k] = v;
        s += v;
    }
    sm[t] = s;
    __syncthreads();
    for (int off = 1; off < BT; off <<= 1) {
        int v = (t >= off) ? sm[t - off] : 0;
        __syncthreads();
        sm[t] += v;
        __syncthreads();
    }
    int run = sm[t] - s;
#pragma unroll
    for (int k = 0; k < 4; ++k) {
        int idx = base4 + k;
        if (idx < NBUCK) {
            lcur[idx] = run;                         // exclusive start
            if (loc[k] > 0)
                gbase[idx] = idx * RSTRIDE + atomicAdd(&bucket_cur[idx], loc[k]);
            run += loc[k];
        }
    }
    __syncthreads();

    // 3. scatter: re-read ei (L2-warm), plain LDS write at start+rank
#pragma unroll
    for (int j = 0; j < EPT; ++j) {
        int idx = j * BT + t;
        if (idx < CHUNK) {
            int e = ebase + idx;
            int src = ei[e];
            int d = ei[NEDGES + e];
            int b = rb[j] >> 14;
            int rank = rb[j] & 0x3fff;
            sorted[lcur[b] + rank] =
                (int)((unsigned)src | ((unsigned)(d & (WB - 1)) << PSHIFT));
        }
    }
    __syncthreads();

    // 4. coalesced flush: largest b with start[b] <= i
    for (int i = t; i < CHUNK; i += BT) {
        int lo = 0, hi = NBUCK - 1;
        while (lo < hi) {
            int mid = (lo + hi + 1) >> 1;
            if (lcur[mid] <= i) lo = mid; else hi = mid - 1;
        }
        recs[(size_t)gbase[lo] + (i - lcur[lo])] = (unsigned)sorted[i];
    }
}

// ---------------- P2b: per-bucket sort-by-node + node_off + gx (round-11 proven) ----------------

__global__ __launch_bounds__(256) void p2b_sort(unsigned int* __restrict__ recs,
                                                const int* __restrict__ bucket_cur,
                                                const float* __restrict__ x,
                                                int* __restrict__ node_off,
                                                float4* __restrict__ gx) {
    __shared__ int sorted[SCAP];
    __shared__ int hist[WB], st[WB], cur[WB];
    int t = threadIdx.x;
    int b = blockIdx.x;
    if (t < WB) hist[t] = 0;
    __syncthreads();

    int beg = b * RSTRIDE;
    int cnt = bucket_cur[b];

    // pass A: local-node histogram
    for (int i = t; i < cnt; i += 256)
        atomicAdd(&hist[recs[(size_t)beg + i] >> PSHIFT], 1);
    __syncthreads();

    // exclusive scan of hist[128]
    if (t < WB) cur[t] = hist[t];
    __syncthreads();
    for (int off = 1; off < WB; off <<= 1) {
        int v = 0;
        if (t < WB && t >= off) v = cur[t - off];
        __syncthreads();
        if (t < WB) cur[t] += v;
        __syncthreads();
    }
    if (t < WB) {
        st[t] = cur[t] - hist[t];
        cur[t] = st[t];
    }
    __syncthreads();

    // pass B: scatter src into LDS by node
    for (int i = t; i < cnt; i += 256) {
        unsigned r = recs[(size_t)beg + i];
        int slot = atomicAdd(&cur[r >> PSHIFT], 1);
        sorted[slot] = (int)(r & SRCMASK);
    }
    __syncthreads();

    // write back sorted src-only records (coalesced)
    for (int i = t; i < cnt; i += 256)
        recs[(size_t)beg + i] = (unsigned)sorted[i];

    // per-node outputs: absolute CSR offset + gx (dinv folded in)
    int node = b * WB + t;
    if (t < WB && node < NNODES) {
        node_off[node] = beg + st[t];
        float di = rsqrtf((float)(1 + hist[t]));
        const float* xr = x + (size_t)node * FIN;
        float4 v0, v1;
        v0.x = xr[0] * di; v0.y = xr[1] * di; v0.z = xr[2] * di; v0.w = xr[3] * di;
        v1.x = xr[4] * di; v1.y = xr[5] * di; v1.z = xr[6] * di; v1.w = 0.0f;
        gx[(size_t)node * 2 + 0] = v0;
        gx[(size_t)node * 2 + 1] = v1;
    }
}

// ---------------- L1: direct-global reduce (no LDS staging) -> MLP ----------------
// recs post-p2b is sorted src-only; the bucket window (~16 KB) is L2-resident,
// so the reduce reads it directly. LDS shrinks to ~8 KB -> up to 8 blocks/CU.

__global__ __launch_bounds__(256, 8) void l1_fast(const unsigned int* __restrict__ recs,
                                                  const int* __restrict__ node_off,
                                                  const int* __restrict__ bucket_cur,
                                                  const float4* __restrict__ gx,
                                                  const float* __restrict__ W1,
                                                  const float* __restrict__ b1,
                                                  const float* __restrict__ W2,
                                                  float4* __restrict__ y) {
    __shared__ int noffs[WB + 1];
    __shared__ float acc[WB][9];
    __shared__ float sW1[FIN * FH1];
    __shared__ float sb1[FH1];
    __shared__ float sW2[FH1 * FH2];
    int t = threadIdx.x;
    for (int i = t; i < FIN * FH1; i += 256) sW1[i] = W1[i];
    if (t < FH1) sb1[t] = b1[t];
    for (int i = t; i < FH1 * FH2; i += 256) sW2[i] = W2[i];

    int b = blockIdx.x;
    int beg = b * RSTRIDE;
    int cnt_all = bucket_cur[b];
    for (int i = t; i < WB; i += 256) {
        int idx = b * WB + i;
        noffs[i] = (idx < NNODES) ? node_off[idx] : beg + cnt_all;
    }
    if (t == 0) noffs[WB] = beg + cnt_all;
    __syncthreads();

    // segmented reduce: 2 lanes per node, registers, unroll 8, direct global reads
    int n = t >> 1;
    int hq = t & 1;
    int base = noffs[n];                 // absolute index into recs
    int cnt = noffs[n + 1] - noffs[n];
    float ax = 0.0f, ay = 0.0f, az = 0.0f, aw = 0.0f;
    int k = 0;
    for (; k + 7 < cnt; k += 8) {
        int s0 = (int)recs[(size_t)base + k];
        int s1 = (int)recs[(size_t)base + k + 1];
        int s2 = (int)recs[(size_t)base + k + 2];
        int s3 = (int)recs[(size_t)base + k + 3];
        int s4 = (int)recs[(size_t)base + k + 4];
        int s5 = (int)recs[(size_t)base + k + 5];
        int s6 = (int)recs[(size_t)base + k + 6];
        int s7 = (int)recs[(size_t)base + k + 7];
        float4 v0 = gx[(size_t)s0 * 2 + hq];
        float4 v1 = gx[(size_t)s1 * 2 + hq];
        float4 v2 = gx[(size_t)s2 * 2 + hq];
        float4 v3 = gx[(size_t)s3 * 2 + hq];
        float4 v4 = gx[(size_t)s4 * 2 + hq];
        float4 v5 = gx[(size_t)s5 * 2 + hq];
        float4 v6 = gx[(size_t)s6 * 2 + hq];
        float4 v7 = gx[(size_t)s7 * 2 + hq];
        ax += v0.x + v1.x; ay += v0.y + v1.y;
        az += v0.z + v1.z; aw += v0.w + v1.w;
        ax += v2.x + v3.x; ay += v2.y + v3.y;
        az += v2.z + v3.z; aw += v2.w + v3.w;
        ax += v4.x + v5.x; ay += v4.y + v5.y;
        az += v4.z + v5.z; aw += v4.w + v5.w;
        ax += v6.x + v7.x; ay += v6.y + v7.y;
        az += v6.z + v7.z; aw += v6.w + v7.w;
    }
    for (; k < cnt; ++k) {
        int s0 = (int)recs[(size_t)base + k];
        float4 v0 = gx[(size_t)s0 * 2 + hq];
        ax += v0.x; ay += v0.y; az += v0.z; aw += v0.w;
    }
    int kb = hq * 4;
    acc[n][kb + 0] = ax; acc[n][kb + 1] = ay;
    acc[n][kb + 2] = az; acc[n][kb + 3] = aw;
    __syncthreads();

    int node = b * WB + t;
    if (t >= WB || node >= NNODES) return;

    float di = rsqrtf((float)(1 + (noffs[t + 1] - noffs[t])));
    float4 g0 = gx[(size_t)node * 2], g1 = gx[(size_t)node * 2 + 1];
    float xa[FIN];
    xa[0] = (acc[t][0] + g0.x) * di;
    xa[1] = (acc[t][1] + g0.y) * di;
    xa[2] = (acc[t][2] + g0.z) * di;
    xa[3] = (acc[t][3] + g0.w) * di;
    xa[4] = (acc[t][4] + g1.x) * di;
    xa[5] = (acc[t][5] + g1.y) * di;
    xa[6] = (acc[t][6] + g1.z) * di;

    float h1[FH1];
#pragma unroll
    for (int j = 0; j < FH1; ++j) h1[j] = sb1[j];
#pragma unroll
    for (int f = 0; f < FIN; ++f) {
        float xv = xa[f];
#pragma unroll
        for (int j = 0; j < FH1; ++j) h1[j] = fmaf(xv, sW1[f * FH1 + j], h1[j]);
    }
#pragma unroll
    for (int j = 0; j < FH1; ++j) h1[j] = fmaxf(h1[j], 0.0f);

    float yv[FH2];
#pragma unroll
    for (int j = 0; j < FH2; ++j) yv[j] = 0.0f;
#pragma unroll
    for (int k2 = 0; k2 < FH1; ++k2) {
        float hv = h1[k2];
#pragma unroll
        for (int j = 0; j < FH2; ++j) yv[j] = fmaf(hv, sW2[k2 * FH2 + j], yv[j]);
    }

    size_t yb = (size_t)node * 4;
    float4 o;
    o.x = yv[0] * di; o.y = yv[1] * di; o.z = yv[2] * di; o.w = yv[3] * di;
    y[yb + 0] = o;
    o.x = yv[4] * di; o.y = yv[5] * di; o.z = yv[6] * di; o.w = yv[7] * di;
    y[yb + 1] = o;
    o.x = yv[8] * di; o.y = yv[9] * di; o.z = yv[10] * di; o.w = yv[11] * di;
    y[yb + 2] = o;
    o.x = yv[12] * di; o.y = yv[13] * di; o.z = yv[14] * di; o.w = yv[15] * di;
    y[yb + 3] = o;
}

// ---------------- L2: direct-global reduce (no LDS staging) -> MLP ----------------

__global__ __launch_bounds__(256, 8) void l2_fast(const unsigned int* __restrict__ recs,
                                                  const int* __restrict__ node_off,
                                                  const int* __restrict__ bucket_cur,
                                                  const float4* __restrict__ y,
                                                  const float* __restrict__ b2,
                                                  const float* __restrict__ Wfc,
                                                  const float* __restrict__ bfc,
                                                  float2* __restrict__ out) {
    __shared__ int noffs[WB + 1];
    __shared__ float acc[WB][17];
    __shared__ float sb2[FH2];
    __shared__ float sWfc[FH2 * NC];
    __shared__ float sbfc[NC];
    int t = threadIdx.x;
    if (t < FH2) sb2[t] = b2[t];
    if (t < FH2 * NC) sWfc[t] = Wfc[t];
    if (t < NC) sbfc[t] = bfc[t];

    int b = blockIdx.x;
    int beg = b * RSTRIDE;
    int cnt_all = bucket_cur[b];
    for (int i = t; i < WB; i += 256) {
        int idx = b * WB + i;
        noffs[i] = (idx < NNODES) ? node_off[idx] : beg + cnt_all;
    }
    if (t == 0) noffs[WB] = beg + cnt_all;
    __syncthreads();

    // segmented reduce: 4 lanes per node, 2 rounds, unroll 8, direct global reads
    int q = t & 3;
#pragma unroll
    for (int r = 0; r < 2; ++r) {
        int n = (t >> 2) + 64 * r;
        int base = noffs[n];             // absolute index into recs
        int cnt = noffs[n + 1] - noffs[n];
        float ax = 0.0f, ay = 0.0f, az = 0.0f, aw = 0.0f;
        int k = 0;
        for (; k + 7 < cnt; k += 8) {
            int s0 = (int)recs[(size_t)base + k];
            int s1 = (int)recs[(size_t)base + k + 1];
            int s2 = (int)recs[(size_t)base + k + 2];
            int s3 = (int)recs[(size_t)base + k + 3];
            int s4 = (int)recs[(size_t)base + k + 4];
            int s5 = (int)recs[(size_t)base + k + 5];
            int s6 = (int)recs[(size_t)base + k + 6];
            int s7 = (int)recs[(size_t)base + k + 7];
            float4 v0 = y[(size_t)s0 * 4 + q];
            float4 v1 = y[(size_t)s1 * 4 + q];
            float4 v2 = y[(size_t)s2 * 4 + q];
            float4 v3 = y[(size_t)s3 * 4 + q];
            float4 v4 = y[(size_t)s4 * 4 + q];
            float4 v5 = y[(size_t)s5 * 4 + q];
            float4 v6 = y[(size_t)s6 * 4 + q];
            float4 v7 = y[(size_t)s7 * 4 + q];
            ax += v0.x + v1.x; ay += v0.y + v1.y;
            az += v0.z + v1.z; aw += v0.w + v1.w;
            ax += v2.x + v3.x; ay += v2.y + v3.y;
            az += v2.z + v3.z; aw += v2.w + v3.w;
            ax += v4.x + v5.x; ay += v4.y + v5.y;
            az += v4.z + v5.z; aw += v4.w + v5.w;
            ax += v6.x + v7.x; ay += v6.y + v7.y;
            az += v6.z + v7.z; aw += v6.w + v7.w;
        }
        for (; k < cnt; ++k) {
            int s0 = (int)recs[(size_t)base + k];
            float4 v0 = y[(size_t)s0 * 4 + q];
            ax += v0.x; ay += v0.y; az += v0.z; aw += v0.w;
        }
        int kb = q * 4;
        acc[n][kb + 0] = ax; acc[n][kb + 1] = ay;
        acc[n][kb + 2] = az; acc[n][kb + 3] = aw;
    }
    __syncthreads();

    int node = b * WB + t;
    if (t >= WB || node >= NNODES) return;

    float di = rsqrtf((float)(1 + (noffs[t + 1] - noffs[t])));
    size_t yb = (size_t)node * 4;
    float4 s0 = y[yb + 0], s1 = y[yb + 1], s2 = y[yb + 2], s3 = y[yb + 3];
    float self[FH2] = {s0.x, s0.y, s0.z, s0.w, s1.x, s1.y, s1.z, s1.w,
                       s2.x, s2.y, s2.z, s2.w, s3.x, s3.y, s3.z, s3.w};

    float o0 = sbfc[0], o1 = sbfc[1];
#pragma unroll
    for (int k = 0; k < FH2; ++k) {
        float h = fmaxf(fmaf(di, acc[t][k] + self[k], sb2[k]), 0.0f);
        o0 = fmaf(h, sWfc[k * NC + 0], o0);
        o1 = fmaf(h, sWfc[k * NC + 1], o1);
    }
    float2 ov; ov.x = o0; ov.y = o1;
    out[node] = ov;
}

// ---------------- launch ----------------

extern "C" void kernel_launch(void* const* d_in, const int* in_sizes, int n_in,
                              void* d_out, int out_size, void* d_ws, size_t ws_size,
                              hipStream_t stream) {
    const float* x   = (const float*)d_in[0];
    const int*   ei  = (const int*)d_in[1];
    const float* W1  = (const float*)d_in[2];
    const float* b1  = (const float*)d_in[3];
    const float* W2  = (const float*)d_in[4];
    const float* b2  = (const float*)d_in[5];
    const float* Wfc = (const float*)d_in[6];
    const float* bfc = (const float*)d_in[7];
    float* out = (float*)d_out;

    char* p = (char*)d_ws;
    auto carve = [&](size_t bytes) -> char* {
        char* r = p;
        p += (bytes + 255) & ~(size_t)255;
        return r;
    };
    int*      bucket_cur = (int*)carve((size_t)NBUCK * 4);
    int*      node_off   = (int*)carve((size_t)NNODES * 4);
    float*    gx         = (float*)carve((size_t)NNODES * 8 * 4);
    float*    y          = (float*)carve((size_t)NNODES * 16 * 4);
    unsigned* recs       = (unsigned*)carve((size_t)NBUCK * RSTRIDE * 4);
    // total ~48.8 MB (unchanged)

    zero_cnt<<<(NBUCK + 255) / 256, 256, 0, stream>>>(bucket_cur);
    p2_sortres<<<NBLK, BT, 0, stream>>>(ei, bucket_cur, recs);
    p2b_sort<<<NBUCK, 256, 0, stream>>>(recs, bucket_cur, x, node_off, (float4*)gx);
    l1_fast<<<NBUCK, 256, 0, stream>>>(recs, node_off, bucket_cur, (const float4*)gx,
                                       W1, b1, W2, (float4*)y);
    l2_fast<<<NBUCK, 256, 0, stream>>>(recs, node_off, bucket_cur, (const float4*)y,
                                       b2, Wfc, bfc, (float2*)out);
}

// Round 14
// 342.964 us; speedup vs baseline: 1.1088x; 1.1088x over previous
//
#include <hip/hip_runtime.h>

#define NNODES 200000
#define NEDGES 6400000
#define FIN 7
#define FH1 32
#define FH2 16
#define NC 2

// bucketing
#define WB 128                       // nodes per bucket
#define WB_SHIFT 7
#define NBUCK ((NNODES + WB - 1) / WB)   // 1563
#define BT 512                        // p2 block threads
#define NBLK 512                      // p2 grid (2 blocks/CU)
#define CHUNK (NEDGES / NBLK)         // 12500 exact
#define EPT ((CHUNK + BT - 1) / BT)   // 25 edges per thread
#define PSHIFT 18
#define SRCMASK ((1u << PSHIFT) - 1)

// padded per-bucket region in recs: mean 4096, sd 64 -> 8-sigma margin
#define RSTRIDE 4608
// per-bucket LDS staging capacity
#define SCAP 5120

// ---------------- zero bucket cursors ----------------

__global__ __launch_bounds__(256) void zero_cnt(int* __restrict__ cnt) {
    int i = blockIdx.x * 256 + threadIdx.x;
    if (i < NBUCK) cnt[i] = 0;
}

// ---------------- P2: rank-capture LDS chunk-sort (spill-free, round-11 proven) ----------------

__global__ __launch_bounds__(BT, 4) void p2_sortres(const int* __restrict__ ei,
                                                    int* __restrict__ bucket_cur,
                                                    unsigned int* __restrict__ recs) {
    __shared__ int sorted[CHUNK];    // 50000 B
    __shared__ int lcur[NBUCK];      // counts -> exclusive starts
    __shared__ int gbase[NBUCK];     // reserved global base per bucket run
    __shared__ int sm[BT];           // scan temp (total 64552 B <= 64K)
    int t = threadIdx.x;
    int blk = blockIdx.x;

    for (int i = t; i < NBUCK; i += BT) lcur[i] = 0;
    __syncthreads();

    // 1. histogram with rank capture: rb[j] = (bucket << 14) | rank
    int ebase = blk * CHUNK;
    int rb[EPT];
#pragma unroll
    for (int j = 0; j < EPT; ++j) {
        int idx = j * BT + t;
        if (idx < CHUNK) {
            int d = ei[NEDGES + ebase + idx];
            int b = d >> WB_SHIFT;
            int rank = atomicAdd(&lcur[b], 1);       // rank < 12500 < 2^14
            rb[j] = (b << 14) | rank;
        }
    }
    __syncthreads();

    // 2. exclusive scan of counts -> starts + global run reservation
    int base4 = t * 4;
    int loc[4];
    int s = 0;
#pragma unroll
    for (int k = 0; k < 4; ++k) {
        int idx = base4 + k;
        int v = (idx < NBUCK) ? lcur[idx] : 0;
        loc[k] = v;
        s += v;
    }
    sm[t] = s;
    __syncthreads();
    for (int off = 1; off < BT; off <<= 1) {
        int v = (t >= off) ? sm[t - off] : 0;
        __syncthreads();
        sm[t] += v;
        __syncthreads();
    }
    int run = sm[t] - s;
#pragma unroll
    for (int k = 0; k < 4; ++k) {
        int idx = base4 + k;
        if (idx < NBUCK) {
            lcur[idx] = run;                         // exclusive start
            if (loc[k] > 0)
                gbase[idx] = idx * RSTRIDE + atomicAdd(&bucket_cur[idx], loc[k]);
            run += loc[k];
        }
    }
    __syncthreads();

    // 3. scatter: re-read ei (L2-warm), plain LDS write at start+rank
#pragma unroll
    for (int j = 0; j < EPT; ++j) {
        int idx = j * BT + t;
        if (idx < CHUNK) {
            int e = ebase + idx;
            int src = ei[e];
            int d = ei[NEDGES + e];
            int b = rb[j] >> 14;
            int rank = rb[j] & 0x3fff;
            sorted[lcur[b] + rank] =
                (int)((unsigned)src | ((unsigned)(d & (WB - 1)) << PSHIFT));
        }
    }
    __syncthreads();

    // 4. coalesced flush: largest b with start[b] <= i
    for (int i = t; i < CHUNK; i += BT) {
        int lo = 0, hi = NBUCK - 1;
        while (lo < hi) {
            int mid = (lo + hi + 1) >> 1;
            if (lcur[mid] <= i) lo = mid; else hi = mid - 1;
        }
        recs[(size_t)gbase[lo] + (i - lcur[lo])] = (unsigned)sorted[i];
    }
}

// ---------------- P2b: per-bucket sort-by-node + node_off + gx (round-9/11 proven) ----------------

__global__ __launch_bounds__(256) void p2b_sort(unsigned int* __restrict__ recs,
                                                const int* __restrict__ bucket_cur,
                                                const float* __restrict__ x,
                                                int* __restrict__ node_off,
                                                float4* __restrict__ gx) {
    __shared__ int sorted[SCAP];
    __shared__ int hist[WB], st[WB], cur[WB];
    int t = threadIdx.x;
    int b = blockIdx.x;
    if (t < WB) hist[t] = 0;
    __syncthreads();

    int beg = b * RSTRIDE;
    int cnt = bucket_cur[b];

    // pass A: local-node histogram
    for (int i = t; i < cnt; i += 256)
        atomicAdd(&hist[recs[(size_t)beg + i] >> PSHIFT], 1);
    __syncthreads();

    // exclusive scan of hist[128]
    if (t < WB) cur[t] = hist[t];
    __syncthreads();
    for (int off = 1; off < WB; off <<= 1) {
        int v = 0;
        if (t < WB && t >= off) v = cur[t - off];
        __syncthreads();
        if (t < WB) cur[t] += v;
        __syncthreads();
    }
    if (t < WB) {
        st[t] = cur[t] - hist[t];
        cur[t] = st[t];
    }
    __syncthreads();

    // pass B: scatter src into LDS by node
    for (int i = t; i < cnt; i += 256) {
        unsigned r = recs[(size_t)beg + i];
        int slot = atomicAdd(&cur[r >> PSHIFT], 1);
        sorted[slot] = (int)(r & SRCMASK);
    }
    __syncthreads();

    // write back sorted src-only records (coalesced)
    for (int i = t; i < cnt; i += 256)
        recs[(size_t)beg + i] = (unsigned)sorted[i];

    // per-node outputs: absolute CSR offset + gx (dinv folded in)
    int node = b * WB + t;
    if (t < WB && node < NNODES) {
        node_off[node] = beg + st[t];
        float di = rsqrtf((float)(1 + hist[t]));
        const float* xr = x + (size_t)node * FIN;
        float4 v0, v1;
        v0.x = xr[0] * di; v0.y = xr[1] * di; v0.z = xr[2] * di; v0.w = xr[3] * di;
        v1.x = xr[4] * di; v1.y = xr[5] * di; v1.z = xr[6] * di; v1.w = 0.0f;
        gx[(size_t)node * 2 + 0] = v0;
        gx[(size_t)node * 2 + 1] = v1;
    }
}

// ---------------- L1: coalesced stage of pre-sorted slice -> register reduce -> MLP ----------------

__global__ __launch_bounds__(256) void l1_fast(const unsigned int* __restrict__ recs,
                                               const int* __restrict__ node_off,
                                               const int* __restrict__ bucket_cur,
                                               const float4* __restrict__ gx,
                                               const float* __restrict__ W1,
                                               const float* __restrict__ b1,
                                               const float* __restrict__ W2,
                                               float4* __restrict__ y) {
    __shared__ int sl_src[SCAP];
    __shared__ int noffs[WB + 1];
    __shared__ float acc[WB][9];
    __shared__ float sW1[FIN * FH1];
    __shared__ float sb1[FH1];
    __shared__ float sW2[FH1 * FH2];
    int t = threadIdx.x;
    for (int i = t; i < FIN * FH1; i += 256) sW1[i] = W1[i];
    if (t < FH1) sb1[t] = b1[t];
    for (int i = t; i < FH1 * FH2; i += 256) sW2[i] = W2[i];

    int b = blockIdx.x;
    int beg = b * RSTRIDE;
    int cnt_all = bucket_cur[b];
    for (int i = t; i < WB; i += 256) {
        int idx = b * WB + i;
        noffs[i] = (idx < NNODES) ? node_off[idx] : beg + cnt_all;
    }
    if (t == 0) noffs[WB] = beg + cnt_all;
    __syncthreads();

    for (int i = t; i < cnt_all; i += 256) sl_src[i] = (int)recs[(size_t)beg + i];
    __syncthreads();

    // segmented reduce: 2 lanes per node, registers, unroll 8
    int n = t >> 1;
    int hq = t & 1;
    int base = noffs[n] - beg;
    int cnt = noffs[n + 1] - noffs[n];
    float ax = 0.0f, ay = 0.0f, az = 0.0f, aw = 0.0f;
    int k = 0;
    for (; k + 7 < cnt; k += 8) {
        int s0 = sl_src[base + k];
        int s1 = sl_src[base + k + 1];
        int s2 = sl_src[base + k + 2];
        int s3 = sl_src[base + k + 3];
        int s4 = sl_src[base + k + 4];
        int s5 = sl_src[base + k + 5];
        int s6 = sl_src[base + k + 6];
        int s7 = sl_src[base + k + 7];
        float4 v0 = gx[(size_t)s0 * 2 + hq];
        float4 v1 = gx[(size_t)s1 * 2 + hq];
        float4 v2 = gx[(size_t)s2 * 2 + hq];
        float4 v3 = gx[(size_t)s3 * 2 + hq];
        float4 v4 = gx[(size_t)s4 * 2 + hq];
        float4 v5 = gx[(size_t)s5 * 2 + hq];
        float4 v6 = gx[(size_t)s6 * 2 + hq];
        float4 v7 = gx[(size_t)s7 * 2 + hq];
        ax += v0.x + v1.x; ay += v0.y + v1.y;
        az += v0.z + v1.z; aw += v0.w + v1.w;
        ax += v2.x + v3.x; ay += v2.y + v3.y;
        az += v2.z + v3.z; aw += v2.w + v3.w;
        ax += v4.x + v5.x; ay += v4.y + v5.y;
        az += v4.z + v5.z; aw += v4.w + v5.w;
        ax += v6.x + v7.x; ay += v6.y + v7.y;
        az += v6.z + v7.z; aw += v6.w + v7.w;
    }
    for (; k < cnt; ++k) {
        int s0 = sl_src[base + k];
        float4 v0 = gx[(size_t)s0 * 2 + hq];
        ax += v0.x; ay += v0.y; az += v0.z; aw += v0.w;
    }
    int kb = hq * 4;
    acc[n][kb + 0] = ax; acc[n][kb + 1] = ay;
    acc[n][kb + 2] = az; acc[n][kb + 3] = aw;
    __syncthreads();

    int node = b * WB + t;
    if (t >= WB || node >= NNODES) return;

    float di = rsqrtf((float)(1 + (noffs[t + 1] - noffs[t])));
    float4 g0 = gx[(size_t)node * 2], g1 = gx[(size_t)node * 2 + 1];
    float xa[FIN];
    xa[0] = (acc[t][0] + g0.x) * di;
    xa[1] = (acc[t][1] + g0.y) * di;
    xa[2] = (acc[t][2] + g0.z) * di;
    xa[3] = (acc[t][3] + g0.w) * di;
    xa[4] = (acc[t][4] + g1.x) * di;
    xa[5] = (acc[t][5] + g1.y) * di;
    xa[6] = (acc[t][6] + g1.z) * di;

    float h1[FH1];
#pragma unroll
    for (int j = 0; j < FH1; ++j) h1[j] = sb1[j];
#pragma unroll
    for (int f = 0; f < FIN; ++f) {
        float xv = xa[f];
#pragma unroll
        for (int j = 0; j < FH1; ++j) h1[j] = fmaf(xv, sW1[f * FH1 + j], h1[j]);
    }
#pragma unroll
    for (int j = 0; j < FH1; ++j) h1[j] = fmaxf(h1[j], 0.0f);

    float yv[FH2];
#pragma unroll
    for (int j = 0; j < FH2; ++j) yv[j] = 0.0f;
#pragma unroll
    for (int k2 = 0; k2 < FH1; ++k2) {
        float hv = h1[k2];
#pragma unroll
        for (int j = 0; j < FH2; ++j) yv[j] = fmaf(hv, sW2[k2 * FH2 + j], yv[j]);
    }

    size_t yb = (size_t)node * 4;
    float4 o;
    o.x = yv[0] * di; o.y = yv[1] * di; o.z = yv[2] * di; o.w = yv[3] * di;
    y[yb + 0] = o;
    o.x = yv[4] * di; o.y = yv[5] * di; o.z = yv[6] * di; o.w = yv[7] * di;
    y[yb + 1] = o;
    o.x = yv[8] * di; o.y = yv[9] * di; o.z = yv[10] * di; o.w = yv[11] * di;
    y[yb + 2] = o;
    o.x = yv[12] * di; o.y = yv[13] * di; o.z = yv[14] * di; o.w = yv[15] * di;
    y[yb + 3] = o;
}

// ---------------- L2: coalesced stage of pre-sorted slice -> register reduce -> MLP ----------------

__global__ __launch_bounds__(256) void l2_fast(const unsigned int* __restrict__ recs,
                                               const int* __restrict__ node_off,
                                               const int* __restrict__ bucket_cur,
                                               const float4* __restrict__ y,
                                               const float* __restrict__ b2,
                                               const float* __restrict__ Wfc,
                                               const float* __restrict__ bfc,
                                               float2* __restrict__ out) {
    __shared__ int sl_src[SCAP];
    __shared__ int noffs[WB + 1];
    __shared__ float acc[WB][17];
    __shared__ float sb2[FH2];
    __shared__ float sWfc[FH2 * NC];
    __shared__ float sbfc[NC];
    int t = threadIdx.x;
    if (t < FH2) sb2[t] = b2[t];
    if (t < FH2 * NC) sWfc[t] = Wfc[t];
    if (t < NC) sbfc[t] = bfc[t];

    int b = blockIdx.x;
    int beg = b * RSTRIDE;
    int cnt_all = bucket_cur[b];
    for (int i = t; i < WB; i += 256) {
        int idx = b * WB + i;
        noffs[i] = (idx < NNODES) ? node_off[idx] : beg + cnt_all;
    }
    if (t == 0) noffs[WB] = beg + cnt_all;
    __syncthreads();

    for (int i = t; i < cnt_all; i += 256) sl_src[i] = (int)recs[(size_t)beg + i];
    __syncthreads();

    // segmented reduce: 4 lanes per node, 2 rounds of 64 nodes, unroll 8
    int q = t & 3;
#pragma unroll
    for (int r = 0; r < 2; ++r) {
        int n = (t >> 2) + 64 * r;
        int base = noffs[n] - beg;
        int cnt = noffs[n + 1] - noffs[n];
        float ax = 0.0f, ay = 0.0f, az = 0.0f, aw = 0.0f;
        int k = 0;
        for (; k + 7 < cnt; k += 8) {
            int s0 = sl_src[base + k];
            int s1 = sl_src[base + k + 1];
            int s2 = sl_src[base + k + 2];
            int s3 = sl_src[base + k + 3];
            int s4 = sl_src[base + k + 4];
            int s5 = sl_src[base + k + 5];
            int s6 = sl_src[base + k + 6];
            int s7 = sl_src[base + k + 7];
            float4 v0 = y[(size_t)s0 * 4 + q];
            float4 v1 = y[(size_t)s1 * 4 + q];
            float4 v2 = y[(size_t)s2 * 4 + q];
            float4 v3 = y[(size_t)s3 * 4 + q];
            float4 v4 = y[(size_t)s4 * 4 + q];
            float4 v5 = y[(size_t)s5 * 4 + q];
            float4 v6 = y[(size_t)s6 * 4 + q];
            float4 v7 = y[(size_t)s7 * 4 + q];
            ax += v0.x + v1.x; ay += v0.y + v1.y;
            az += v0.z + v1.z; aw += v0.w + v1.w;
            ax += v2.x + v3.x; ay += v2.y + v3.y;
            az += v2.z + v3.z; aw += v2.w + v3.w;
            ax += v4.x + v5.x; ay += v4.y + v5.y;
            az += v4.z + v5.z; aw += v4.w + v5.w;
            ax += v6.x + v7.x; ay += v6.y + v7.y;
            az += v6.z + v7.z; aw += v6.w + v7.w;
        }
        for (; k < cnt; ++k) {
            int s0 = sl_src[base + k];
            float4 v0 = y[(size_t)s0 * 4 + q];
            ax += v0.x; ay += v0.y; az += v0.z; aw += v0.w;
        }
        int kb = q * 4;
        acc[n][kb + 0] = ax; acc[n][kb + 1] = ay;
        acc[n][kb + 2] = az; acc[n][kb + 3] = aw;
    }
    __syncthreads();

    int node = b * WB + t;
    if (t >= WB || node >= NNODES) return;

    float di = rsqrtf((float)(1 + (noffs[t + 1] - noffs[t])));
    size_t yb = (size_t)node * 4;
    float4 s0 = y[yb + 0], s1 = y[yb + 1], s2 = y[yb + 2], s3 = y[yb + 3];
    float self[FH2] = {s0.x, s0.y, s0.z, s0.w, s1.x, s1.y, s1.z, s1.w,
                       s2.x, s2.y, s2.z, s2.w, s3.x, s3.y, s3.z, s3.w};

    float o0 = sbfc[0], o1 = sbfc[1];
#pragma unroll
    for (int k = 0; k < FH2; ++k) {
        float h = fmaxf(fmaf(di, acc[t][k] + self[k], sb2[k]), 0.0f);
        o0 = fmaf(h, sWfc[k * NC + 0], o0);
        o1 = fmaf(h, sWfc[k * NC + 1], o1);
    }
    float2 ov; ov.x = o0; ov.y = o1;
    out[node] = ov;
}

// ---------------- launch ----------------

extern "C" void kernel_launch(void* const* d_in, const int* in_sizes, int n_in,
                              void* d_out, int out_size, void* d_ws, size_t ws_size,
                              hipStream_t stream) {
    const float* x   = (const float*)d_in[0];
    const int*   ei  = (const int*)d_in[1];
    const float* W1  = (const float*)d_in[2];
    const float* b1  = (const float*)d_in[3];
    const float* W2  = (const float*)d_in[4];
    const float* b2  = (const float*)d_in[5];
    const float* Wfc = (const float*)d_in[6];
    const float* bfc = (const float*)d_in[7];
    float* out = (float*)d_out;

    char* p = (char*)d_ws;
    auto carve = [&](size_t bytes) -> char* {
        char* r = p;
        p += (bytes + 255) & ~(size_t)255;
        return r;
    };
    int*      bucket_cur = (int*)carve((size_t)NBUCK * 4);
    int*      node_off   = (int*)carve((size_t)NNODES * 4);
    float*    gx         = (float*)carve((size_t)NNODES * 8 * 4);
    float*    y          = (float*)carve((size_t)NNODES * 16 * 4);
    unsigned* recs       = (unsigned*)carve((size_t)NBUCK * RSTRIDE * 4);
    // total ~48.8 MB

    zero_cnt<<<(NBUCK + 255) / 256, 256, 0, stream>>>(bucket_cur);
    p2_sortres<<<NBLK, BT, 0, stream>>>(ei, bucket_cur, recs);
    p2b_sort<<<NBUCK, 256, 0, stream>>>(recs, bucket_cur, x, node_off, (float4*)gx);
    l1_fast<<<NBUCK, 256, 0, stream>>>(recs, node_off, bucket_cur, (const float4*)gx,
                                       W1, b1, W2, (float4*)y);
    l2_fast<<<NBUCK, 256, 0, stream>>>(recs, node_off, bucket_cur, (const float4*)y,
                                       b2, Wfc, bfc, (float2*)out);
}